// Round 1
// 802.809 us; speedup vs baseline: 1.1064x; 1.1064x over previous
//
#include <hip/hip_runtime.h>
#include <math.h>

// ---------- types ----------
typedef __bf16 bf16x8 __attribute__((ext_vector_type(8)));
typedef float f32x4 __attribute__((ext_vector_type(4)));
typedef unsigned short us4v __attribute__((ext_vector_type(4)));
typedef unsigned short us8v __attribute__((ext_vector_type(8)));

#define NTOK 65536   // B*S = 8*8192 tokens
#define DMODEL 512

// round-to-nearest-even f32 -> bf16 bits
__device__ __forceinline__ unsigned short f2bf(float f) {
  unsigned int u = __float_as_uint(f);
  u += 0x7fffu + ((u >> 16) & 1u);
  return (unsigned short)(u >> 16);
}

// fast tanh-GELU: x * u/(u+1), u = exp(2*0.7978845608*(x + 0.044715 x^3))
// max |diff vs erf-gelu| ~1e-3, well inside threshold margin
__device__ __forceinline__ float gelu_fast(float x) {
  float x3 = x * x * x;
  float u = __expf(1.5957691216057308f * (x + 0.044715f * x3));
  return x * __fdividef(u, u + 1.0f);
}

// async global->LDS, 16B per lane; LDS dest is wave-uniform base (+lane*16 by HW)
__device__ __forceinline__ void async16(const void* g, void* l) {
  __builtin_amdgcn_global_load_lds((const __attribute__((address_space(1))) void*)g,
                                   (__attribute__((address_space(3))) void*)l,
                                   16, 0, 0);
}

// ---------- fp32 -> bf16 weight conversion ----------
__global__ __launch_bounds__(256) void cvt_bf16_kernel(const float4* __restrict__ in,
                                                       us4v* __restrict__ out, int n4) {
  int i = blockIdx.x * 256 + threadIdx.x;
  if (i < n4) {
    float4 v = in[i];
    us4v o;
    o.x = f2bf(v.x); o.y = f2bf(v.y); o.z = f2bf(v.z); o.w = f2bf(v.w);
    out[i] = o;
  }
}

// ---------- LayerNorm: one wave per 512-float row, bf16 output ----------
__global__ __launch_bounds__(256) void ln_kernel(const float* __restrict__ x,
                                                 const float* __restrict__ g,
                                                 const float* __restrict__ b,
                                                 unsigned short* __restrict__ out) {
  const int w = threadIdx.x >> 6;
  const int lane = threadIdx.x & 63;
  const size_t row = (size_t)blockIdx.x * 4 + w;
  const float4* xv = (const float4*)(x + row * DMODEL);
  float4 v0 = xv[lane * 2];
  float4 v1 = xv[lane * 2 + 1];
  float s  = v0.x + v0.y + v0.z + v0.w + v1.x + v1.y + v1.z + v1.w;
  float ss = v0.x*v0.x + v0.y*v0.y + v0.z*v0.z + v0.w*v0.w
           + v1.x*v1.x + v1.y*v1.y + v1.z*v1.z + v1.w*v1.w;
#pragma unroll
  for (int m = 1; m < 64; m <<= 1) {
    s  += __shfl_xor(s, m, 64);
    ss += __shfl_xor(ss, m, 64);
  }
  const float mean = s * (1.0f / DMODEL);
  const float var  = ss * (1.0f / DMODEL) - mean * mean;
  const float rstd = rsqrtf(var + 1e-5f);
  const int c = lane * 8;
  const float4* gv = (const float4*)(g + c);
  const float4* bv = (const float4*)(b + c);
  float4 g0 = gv[0], g1 = gv[1], bb0 = bv[0], bb1 = bv[1];
  us8v o;
  o[0] = f2bf((v0.x - mean) * rstd * g0.x + bb0.x);
  o[1] = f2bf((v0.y - mean) * rstd * g0.y + bb0.y);
  o[2] = f2bf((v0.z - mean) * rstd * g0.z + bb0.z);
  o[3] = f2bf((v0.w - mean) * rstd * g0.w + bb0.w);
  o[4] = f2bf((v1.x - mean) * rstd * g1.x + bb1.x);
  o[5] = f2bf((v1.y - mean) * rstd * g1.y + bb1.y);
  o[6] = f2bf((v1.z - mean) * rstd * g1.z + bb1.z);
  o[7] = f2bf((v1.w - mean) * rstd * g1.w + bb1.w);
  *(us8v*)(out + row * DMODEL + c) = o;
}

// ---------- bf16 GEMM: C[M,N] = A[M,K] @ B[N,K]^T (+bias)(+resid)(+gelu) ----------
// 1-D grid = (M/128)*(N/128); block = 256 (4 waves, 2x2 wave grid, 64x64 per wave)
// BK=64, XOR-swizzled LDS: 16B unit (r,kg) stored at unit index r*8 + (kg ^ (r&7))
//   -> conflict-free ds_read_b128 (each quad's 16 lanes cover all 32 banks 2-way)
// EPI: 0 = +bias+resid, 1 = +bias then gelu, 2 = +bias
// EXPERT: per-128-row-tile weight/bias block selected by (row/4096)&7
//
// XCD band scheduling: HW dispatches block n -> XCD n%8 (round-robin heuristic).
// We remap so XCD x processes contiguous work w = x*(total/8) + n/8, and work
// order within an XCD walks one row-band (band_rows row-tiles) across ALL column
// tiles before moving to the next band.  One band (128ish blocks) ~= one XCD's
// residency, so its A-slab (1-2 MB) + that XCD's expert weights (4 MB max, 2
// experts per XCD by construction) stay L2-resident -> A fetched from HBM once
// instead of ncol times.  Bands are expert-aligned (band_rows*128 divides 4096).
template <int EPI, bool EXPERT, typename OutT, int K>
__global__ __launch_bounds__(256, 2) void gemm_bt2(
    const unsigned short* __restrict__ A, const unsigned short* __restrict__ B,
    const float* __restrict__ bias, const float* __restrict__ resid,
    OutT* __restrict__ C, int N) {
  __shared__ alignas(16) unsigned short tA[128 * 64];
  __shared__ alignas(16) unsigned short tB[128 * 64];
  const int tid = threadIdx.x;
  const int w = tid >> 6;
  const int lane = tid & 63;
  const int wm = w & 1, wn = w >> 1;
  const int quad = lane >> 4, lm = lane & 15;

  // ---- XCD-aware band block swizzle ----
  const int ncol = N >> 7;                 // 4 or 16 column tiles
  const int perx = gridDim.x >> 3;         // blocks per XCD chunk (grid % 8 == 0)
  const int xcd = blockIdx.x & 7;
  const int wk = xcd * perx + (blockIdx.x >> 3);
  const int band_rows = (ncol == 16) ? 8 : 16;  // ~128/64 blocks per band
  const int bb = band_rows * ncol;
  const int band = wk / bb;
  const int rem = wk - band * bb;
  const int ct = rem / band_rows;          // column tile
  const int rib = rem - ct * band_rows;    // row tile within band
  const size_t row0 = (size_t)(band * band_rows + rib) * 128;
  const int col0 = ct * 128;

  const unsigned short* Bp = B;
  const float* biasp = bias;
  if (EXPERT) {
    const int e = (int)((row0 >> 12) & 7);  // (token/4096) % 8
    Bp += (size_t)e * (size_t)N * (size_t)K;
    biasp += (size_t)e * (size_t)N;
  }

  // staging: 16 chunks of 1 KiB per tile (4 per wave); chunk c covers units
  // [c*64, c*64+64); lane l writes unit c*64+l = (r, slot u); source k-unit
  // kg = u ^ (r&7)  (XOR swizzle), so global reads stay within one 128B row slice.
  const unsigned short* gA[4];
  const unsigned short* gB[4];
  unsigned short* lA[4];
  unsigned short* lB[4];
#pragma unroll
  for (int j = 0; j < 4; ++j) {
    const int c = w * 4 + j;
    const int f = c * 64 + lane;
    const int r = f >> 3;
    const int u = f & 7;
    const int kg = u ^ (r & 7);
    gA[j] = A + (row0 + (size_t)r) * (size_t)K + kg * 8;
    gB[j] = Bp + ((size_t)col0 + (size_t)r) * (size_t)K + kg * 8;
    lA[j] = tA + c * 512;
    lB[j] = tB + c * 512;
  }

  f32x4 acc[4][4] = {};

  for (int k0 = 0; k0 < K; k0 += 64) {
#pragma unroll
    for (int j = 0; j < 4; ++j) {
      async16(gA[j], lA[j]);
      async16(gB[j], lB[j]);
      gA[j] += 64;
      gB[j] += 64;
    }
    __syncthreads();
    bf16x8 af[2][4], bfr[2][4];
#pragma unroll
    for (int s = 0; s < 2; ++s) {
#pragma unroll
      for (int mi = 0; mi < 4; ++mi) {
        const int r = wm * 64 + mi * 16 + lm;
        af[s][mi] = *(const bf16x8*)&tA[(r * 8 + ((s * 4 + quad) ^ (r & 7))) * 8];
      }
#pragma unroll
      for (int ni = 0; ni < 4; ++ni) {
        const int cc = wn * 64 + ni * 16 + lm;
        bfr[s][ni] = *(const bf16x8*)&tB[(cc * 8 + ((s * 4 + quad) ^ (cc & 7))) * 8];
      }
    }
#pragma unroll
    for (int s = 0; s < 2; ++s)
#pragma unroll
      for (int mi = 0; mi < 4; ++mi)
#pragma unroll
        for (int ni = 0; ni < 4; ++ni)
          acc[mi][ni] =
              __builtin_amdgcn_mfma_f32_16x16x32_bf16(af[s][mi], bfr[s][ni], acc[mi][ni], 0, 0, 0);
    __syncthreads();
  }

  // epilogue: C/D layout col=lane&15, row=quad*4+r
#pragma unroll
  for (int mi = 0; mi < 4; ++mi) {
#pragma unroll
    for (int ni = 0; ni < 4; ++ni) {
      const int col = col0 + wn * 64 + ni * 16 + lm;
      const float bv = biasp[col];
#pragma unroll
      for (int r = 0; r < 4; ++r) {
        const size_t grow = row0 + (size_t)(wm * 64 + mi * 16 + quad * 4 + r);
        float v = acc[mi][ni][r] + bv;
        if constexpr (EPI == 0) v += resid[grow * (size_t)N + col];
        if constexpr (EPI == 1) v = gelu_fast(v);
        if constexpr (sizeof(OutT) == 4) {
          C[grow * (size_t)N + col] = v;             // fp32 store (d_out is float*)
        } else {
          C[grow * (size_t)N + col] = (OutT)f2bf(v); // bf16 store (intermediates)
        }
      }
    }
  }
}

// ---------- launch ----------
extern "C" void kernel_launch(void* const* d_in, const int* in_sizes, int n_in,
                              void* d_out, int out_size, void* d_ws, size_t ws_size,
                              hipStream_t stream) {
  const float* x      = (const float*)d_in[0];
  const float* ln_g   = (const float*)d_in[1];
  const float* ln_b   = (const float*)d_in[2];
  const float* attn_w = (const float*)d_in[3];
  const float* attn_b = (const float*)d_in[4];
  // d_in[5] = gate_w : logits/top-k are dead code for the output -> skipped
  const float* fc1_w  = (const float*)d_in[6];
  const float* fc1_b  = (const float*)d_in[7];
  const float* fc2_w  = (const float*)d_in[8];
  const float* fc2_b  = (const float*)d_in[9];
  const float* next_w = (const float*)d_in[10];
  const float* next_b = (const float*)d_in[11];

  char* ws = (char*)d_ws;
  const size_t MB = 1024ull * 1024ull;
  unsigned short* wN    = (unsigned short*)(ws);             // 64 MiB: normed, later y
  unsigned short* wXat  = (unsigned short*)(ws + 64 * MB);   // 64 MiB: x_attn (bf16)
  unsigned short* wH    = (unsigned short*)(ws + 128 * MB);  // 256 MiB: gelu(h) (bf16)
  unsigned short* attnbf = (unsigned short*)(ws + 384 * MB); // 0.5 MiB
  unsigned short* fc1bf  = (unsigned short*)(ws + 385 * MB); // 16 MiB
  unsigned short* fc2bf  = (unsigned short*)(ws + 401 * MB); // 16 MiB
  unsigned short* nextbf = (unsigned short*)(ws + 417 * MB); // 0.5 MiB

  // weights fp32 -> bf16 (cheap: ~17.3M elements)
  {
    int n4;
    n4 = (512 * 512) / 4;
    cvt_bf16_kernel<<<dim3((n4 + 255) / 256), dim3(256), 0, stream>>>((const float4*)attn_w, (us4v*)attnbf, n4);
    n4 = (8 * 2048 * 512) / 4;
    cvt_bf16_kernel<<<dim3((n4 + 255) / 256), dim3(256), 0, stream>>>((const float4*)fc1_w, (us4v*)fc1bf, n4);
    n4 = (8 * 512 * 2048) / 4;
    cvt_bf16_kernel<<<dim3((n4 + 255) / 256), dim3(256), 0, stream>>>((const float4*)fc2_w, (us4v*)fc2bf, n4);
    n4 = (512 * 512) / 4;
    cvt_bf16_kernel<<<dim3((n4 + 255) / 256), dim3(256), 0, stream>>>((const float4*)next_w, (us4v*)nextbf, n4);
  }

  // LayerNorm -> wN (bf16 normed)
  ln_kernel<<<dim3(NTOK / 4), dim3(256), 0, stream>>>(x, ln_g, ln_b, wN);

  // x_attn = normed @ attn_w^T + attn_b + x   -> wXat (bf16)
  gemm_bt2<0, false, unsigned short, 512><<<dim3((NTOK / 128) * 4), dim3(256), 0, stream>>>(
      wN, attnbf, attn_b, x, wXat, 512);

  // h = gelu(x_attn @ fc1_w[e]^T + fc1_b[e])  -> wH (bf16)
  gemm_bt2<1, true, unsigned short, 512><<<dim3((NTOK / 128) * 16), dim3(256), 0, stream>>>(
      wXat, fc1bf, fc1_b, nullptr, wH, 2048);

  // y = h @ fc2_w[e]^T + fc2_b[e]             -> wN (bf16, reuse)
  gemm_bt2<2, true, unsigned short, 2048><<<dim3((NTOK / 128) * 4), dim3(256), 0, stream>>>(
      wH, fc2bf, fc2_b, nullptr, wN, 512);

  // out = gelu(y @ next_w^T + next_b)         -> d_out (fp32)
  gemm_bt2<1, false, float, 512><<<dim3((NTOK / 128) * 4), dim3(256), 0, stream>>>(
      wN, nextbf, next_b, nullptr, (float*)d_out, 512);
}